// Round 5
// baseline (654.640 us; speedup 1.0000x reference)
//
#include <hip/hip_runtime.h>
#include <math.h>

// Problem constants (from reference): B=64, Q=900, T=128, NUM_CLASSES=13
#define B_    64
#define Q_    900
#define T_    128
#define NCLS  13
#define NCLS1 14
#define NTH   256
#define NWV   (NTH / 64)
#define NK    15          // fallback scan: q = lane + 64*k, k<NK
#define LCAND 16          // per-row candidate-list length

// Block-wide f64 sum; result valid on tid 0. All threads must call.
__device__ __forceinline__ double blockSum(double v, double* sAcc, int tid) {
#pragma unroll
    for (int off = 32; off > 0; off >>= 1) v += __shfl_down(v, off);
    if ((tid & 63) == 0) sAcc[tid >> 6] = v;
    __syncthreads();
    if (tid == 0) {
#pragma unroll
        for (int w = 1; w < NWV; ++w) v += sAcc[w];
    }
    __syncthreads();
    return v;
}

// f32 cost entry, identical op order to the jnp reference:
// (|dx|+|dy|+|dz|+|dw| summed left-to-right) - prob[lab].
__device__ __forceinline__ float costQ(const float4 p4, const float4 t4, const float pr) {
    float cb = fabsf(p4.x - t4.x);
    cb = cb + fabsf(p4.y - t4.y);
    cb = cb + fabsf(p4.z - t4.z);
    cb = cb + fabsf(p4.w - t4.w);
    return cb - pr;
}

// One block per image. Exact JV via lazy/sparse Dijkstra:
//  - row-reduction u[r]=min_j c(r,j) + greedy zero-reduced-cost init
//  - SSP passes where only MATCHED columns (<=128, slot=matched row) carry
//    explicit distances (registers, 2 slots/lane); inactive columns (v==0)
//    are represented lazily by each reached row's cheapest inactive candidate
//    from its precomputed top-16 list (exact full-scan fallback when the
//    list is exhausted). Popping an inactive column == augmenting path found.
//  - deferred dual updates (v[c]+=d-dT, u[r]+=dT-d) == e-maxx incremental.
// Unique optimum for continuous random costs => identical assignment to the
// reference's e-maxx JV on the same f32 cost entries.
extern "C" __global__ __launch_bounds__(NTH, 1)
void detr_hungarian_loss(const float* __restrict__ pc,    // [B,Q,14]
                         const float* __restrict__ pbx,   // [B,Q,4]
                         const int*   __restrict__ tl,    // [B,T]
                         const float* __restrict__ tbx,   // [B,T,4]
                         float* __restrict__ out)         // [1], poisoned 0xAA
{
    const int b   = blockIdx.x;
    const int tid = threadIdx.x;

    __shared__ float  sProb[Q_ * NCLS];   // softmax probs, classes 0..12
    __shared__ float  sLse[Q_];           // logsumexp per query (for CE)
    __shared__ float4 sPb4[Q_];           // predicted boxes
    __shared__ float4 sTb4[T_];           // target boxes
    __shared__ int    sLab[T_];           // target labels
    __shared__ double sVcol[Q_];          // column duals (0 unless ever-used)
    __shared__ int    sColMatch[Q_];      // col -> row+1, 0 = free
    __shared__ int    sMatchCol[T_];      // row -> col, -1 = unmatched
    __shared__ int    sWayRow[T_];        // Dijkstra parent slot per row-slot
    __shared__ double sUr[T_];            // row duals
    __shared__ float  sCandC[T_ * LCAND]; // per-row top-16 costs (ascending)
    __shared__ int    sCandJ[T_ * LCAND]; // per-row top-16 columns
    __shared__ int    sFree[T_];
    __shared__ int    sNF;
    __shared__ int    sPred[T_];          // target t -> matched query
    __shared__ int    sTc[Q_];            // per-query CE target class
    __shared__ double sAcc[NWV];

    const double DINF = __builtin_inf();

    const float* pcb = pc  + (size_t)b * Q_ * NCLS1;
    const float* pbb = pbx + (size_t)b * Q_ * 4;
    const float* tbb = tbx + (size_t)b * T_ * 4;
    const int*   tlb = tl  + (size_t)b * T_;

    // ---- stage inputs + f32 softmax (same op order as jax.nn.softmax) ----
    for (int q = tid; q < Q_; q += NTH) {
        float x[NCLS1];
#pragma unroll
        for (int c = 0; c < NCLS1; ++c) x[c] = pcb[q * NCLS1 + c];
        float mx = x[0];
#pragma unroll
        for (int c = 1; c < NCLS1; ++c) mx = fmaxf(mx, x[c]);
        float ex[NCLS1];
        float sum = 0.f;
#pragma unroll
        for (int c = 0; c < NCLS1; ++c) { ex[c] = expf(x[c] - mx); sum += ex[c]; }
#pragma unroll
        for (int c = 0; c < NCLS; ++c) sProb[q * NCLS + c] = ex[c] / sum;
        sLse[q] = mx + logf(sum);
        sPb4[q] = reinterpret_cast<const float4*>(pbb)[q];
        sVcol[q] = 0.0;
        sColMatch[q] = 0;
    }
    for (int t = tid; t < T_; t += NTH) {
        sLab[t] = tlb[t];
        sTb4[t] = reinterpret_cast<const float4*>(tbb)[t];
        sMatchCol[t] = -1;
    }
    __syncthreads();

    // ---- per-row top-16 candidate list (sorted ascending, stable ties) ----
    if (tid < T_) {
        const int r = tid;
        const float4 t4  = sTb4[r];
        const int    lab = sLab[r];
        float bc[LCAND]; int bj[LCAND];
#pragma unroll
        for (int k = 0; k < LCAND; ++k) { bc[k] = 1e38f; bj[k] = -1; }
        for (int q = 0; q < Q_; ++q) {
            const float c = costQ(sPb4[q], t4, sProb[q * NCLS + lab]);
            if (c < bc[LCAND - 1]) {
                int pos = 0;
#pragma unroll
                for (int k = 0; k < LCAND; ++k) pos += (bc[k] <= c) ? 1 : 0;
#pragma unroll
                for (int k = LCAND - 1; k >= 1; --k) {
                    if (k > pos) { bc[k] = bc[k - 1]; bj[k] = bj[k - 1]; }
                }
#pragma unroll
                for (int k = 0; k < LCAND; ++k) {
                    if (k == pos) { bc[k] = c; bj[k] = q; }
                }
            }
        }
#pragma unroll
        for (int k = 0; k < LCAND; ++k) {
            sCandC[r * LCAND + k] = bc[k];
            sCandJ[r * LCAND + k] = bj[k];
        }
    }
    __syncthreads();

    // ================= wave 0 only: greedy + lazy-Dijkstra SSP =============
    if (tid < 64) {
        const int lane = tid;

        // greedy zero-reduced-cost init (lane 0, serial)
        if (lane == 0) {
            int nf = 0;
            for (int r = 0; r < T_; ++r) {
                sUr[r] = (double)sCandC[r * LCAND];     // row min
                const int j = sCandJ[r * LCAND];        // row argmin (top-1)
                if (sColMatch[j] == 0) { sColMatch[j] = r + 1; sMatchCol[r] = j; }
                else                   { sFree[nf++] = r; }
            }
            sNF = nf;
        }
        __builtin_amdgcn_wave_barrier();
        const int nf = sNF;

        for (int fi = 0; fi < nf; ++fi) {
            const int rf = sFree[fi];
            int    colr[2];   // column matched to my slots (pass-start snapshot)
            double dreg[2];
            bool   pop[2];
#pragma unroll
            for (int h = 0; h < 2; ++h) {
                colr[h] = sMatchCol[lane + (h << 6)];
                dreg[h] = DINF;
                pop[h]  = false;
            }
            double bestI = DINF; int bestICol = -1, bestIPar = -2;
            int    curRow = rf;  double curA = -sUr[rf]; int curPar = -1;
            double dT = 0.0;     bool terminal = false;

            for (int it = 0; it < 140; ++it) {
                const float4 t4  = sTb4[curRow];
                const int    lab = sLab[curRow];
                // relax owned active (matched) slots
#pragma unroll
                for (int h = 0; h < 2; ++h) {
                    const int col = colr[h];
                    if (col >= 0 && !pop[h]) {
                        const float  c   = costQ(sPb4[col], t4, sProb[col * NCLS + lab]);
                        const double cur = curA + (double)c - sVcol[col];
                        if (cur < dreg[h]) { dreg[h] = cur; sWayRow[lane + (h << 6)] = curPar; }
                    }
                }
                // cheapest inactive candidate of curRow (v==0 for inactive)
                double cv = DINF; int ccol = -1;
                if (lane < LCAND) {
                    const int col = sCandJ[curRow * LCAND + lane];
                    if (col >= 0 && sColMatch[col] == 0) {
                        cv = curA + (double)sCandC[curRow * LCAND + lane];
                        ccol = col;
                    }
                }
#pragma unroll
                for (int m = 1; m < 64; m <<= 1) {
                    const double ov = __shfl_xor(cv, m);
                    const int    oc = __shfl_xor(ccol, m);
                    if (ov < cv || (ov == cv && oc >= 0 && (ccol < 0 || oc < ccol))) { cv = ov; ccol = oc; }
                }
                if (ccol < 0) {   // list exhausted: exact full scan over free cols
                    double fv = DINF; int fc = -1;
#pragma unroll
                    for (int k = 0; k < NK; ++k) {
                        const int q = (k << 6) + lane;
                        if (q < Q_ && sColMatch[q] == 0) {
                            const float  c  = costQ(sPb4[q], t4, sProb[q * NCLS + lab]);
                            const double cu = curA + (double)c;
                            if (cu < fv) { fv = cu; fc = q; }
                        }
                    }
#pragma unroll
                    for (int m = 1; m < 64; m <<= 1) {
                        const double ov = __shfl_xor(fv, m);
                        const int    oc = __shfl_xor(fc, m);
                        if (ov < fv || (ov == fv && oc >= 0 && (fc < 0 || oc < fc))) { fv = ov; fc = oc; }
                    }
                    cv = fv; ccol = fc;
                }
                if (cv < bestI) { bestI = cv; bestICol = ccol; bestIPar = curPar; }

                // pop argmin over active un-popped slots
                double pm = DINF; int ps = -1;
#pragma unroll
                for (int h = 0; h < 2; ++h) {
                    if (colr[h] >= 0 && !pop[h] && dreg[h] < pm) { pm = dreg[h]; ps = lane + (h << 6); }
                }
#pragma unroll
                for (int m = 1; m < 64; m <<= 1) {
                    const double ov = __shfl_xor(pm, m);
                    const int    os = __shfl_xor(ps, m);
                    if (ov < pm || (ov == pm && os >= 0 && (ps < 0 || os < ps))) { pm = ov; ps = os; }
                }
                if (bestI <= pm || ps < 0) { terminal = (bestICol >= 0); dT = bestI; break; }
                if ((ps & 63) == lane) pop[ps >> 6] = true;
                curRow = ps; curA = pm - sUr[ps]; curPar = ps;
            }
            __builtin_amdgcn_wave_barrier();

            if (terminal) {
                // deferred dual updates (== e-maxx incremental totals)
#pragma unroll
                for (int h = 0; h < 2; ++h) {
                    if (pop[h]) {
                        const int s = lane + (h << 6);
                        sVcol[colr[h]] += dreg[h] - dT;
                        sUr[s]         += dT - dreg[h];
                    }
                }
                if (lane == 0) sUr[rf] += dT;
                __builtin_amdgcn_wave_barrier();
                if (lane == 0) {   // augment along parent chain
                    int col = bestICol, s = bestIPar, guard = 0;
                    while (s >= 0 && guard++ < 140) {
                        const int oldcol = sMatchCol[s];
                        sMatchCol[s] = col; sColMatch[col] = s + 1;
                        col = oldcol; s = sWayRow[s];
                    }
                    sMatchCol[rf] = col; sColMatch[col] = rf + 1;
                }
            }
            __builtin_amdgcn_wave_barrier();
        }

        // safety fix-up: any unmatched row grabs a free column (shouldn't hit)
        if (lane == 0) {
            for (int r = 0; r < T_; ++r) {
                if (sMatchCol[r] < 0) {
                    for (int q = 0; q < Q_; ++q) {
                        if (sColMatch[q] == 0) { sColMatch[q] = r + 1; sMatchCol[r] = q; break; }
                    }
                }
            }
        }
    }
    __syncthreads();

    // ---- matching result: target t <-> query sMatchCol[t] ----
    for (int t = tid; t < T_; t += NTH) sPred[t] = sMatchCol[t];
    for (int q = tid; q < Q_; q += NTH) sTc[q] = NCLS;
    __syncthreads();
    for (int t = tid; t < T_; t += NTH) sTc[sPred[t]] = sLab[t];  // sPred distinct
    __syncthreads();

    // ---- weighted CE over all queries ----
    double swn = 0.0, sw = 0.0;
    for (int q = tid; q < Q_; q += NTH) {
        const int   c   = sTc[q];
        const float xv  = pcb[q * NCLS1 + c];
        const float nll = sLse[q] - xv;              // -log_softmax[tc]
        const double w  = (c == NCLS) ? (double)0.05f : 1.0;
        swn += w * (double)nll;
        sw  += w;
    }

    // ---- bbox L1 + GIoU over matched pairs ----
    double l1s = 0.0, gs = 0.0;
    for (int t = tid; t < T_; t += NTH) {
        const int q = sPred[t];
        const float4 p4 = sPb4[q];
        const float4 t4 = sTb4[t];
        l1s += (double)fabsf(p4.x - t4.x) + (double)fabsf(p4.y - t4.y)
             + (double)fabsf(p4.z - t4.z) + (double)fabsf(p4.w - t4.w);
        const float ax1 = p4.x - 0.5f * p4.z, ay1 = p4.y - 0.5f * p4.w;
        const float ax2 = p4.x + 0.5f * p4.z, ay2 = p4.y + 0.5f * p4.w;
        const float bx1 = t4.x - 0.5f * t4.z, by1 = t4.y - 0.5f * t4.w;
        const float bx2 = t4.x + 0.5f * t4.z, by2 = t4.y + 0.5f * t4.w;
        const double a1 = (double)(ax2 - ax1) * (double)(ay2 - ay1);
        const double a2 = (double)(bx2 - bx1) * (double)(by2 - by1);
        const double ltx = fmax((double)ax1, (double)bx1);
        const double lty = fmax((double)ay1, (double)by1);
        const double rbx = fmin((double)ax2, (double)bx2);
        const double rby = fmin((double)ay2, (double)by2);
        const double iw = fmax(rbx - ltx, 0.0), ih = fmax(rby - lty, 0.0);
        const double inter = iw * ih;
        const double uni   = a1 + a2 - inter;
        const double iou   = inter / uni;
        const double cx1 = fmin((double)ax1, (double)bx1);
        const double cy1 = fmin((double)ay1, (double)by1);
        const double cx2 = fmax((double)ax2, (double)bx2);
        const double cy2 = fmax((double)ay2, (double)by2);
        const double ac  = (cx2 - cx1) * (cy2 - cy1);
        const double giou = iou - (ac - uni) / ac;
        gs += 1.0 - giou;
    }

    const double swnT = blockSum(swn, sAcc, tid);
    const double swT  = blockSum(sw,  sAcc, tid);
    const double l1T  = blockSum(l1s, sAcc, tid);
    const double gsT  = blockSum(gs,  sAcc, tid);
    if (tid == 0) {
        const double cls = swnT / swT;
        const double bb  = 5.0 * (l1T / (double)(T_ * 4)) + 2.0 * (gsT / (double)T_);
        const double mine = (cls + bb) / 8192.0;
        // fused finalize: first CAS converts the 0xAA poison to 0.0 exactly
        // once (each block CASes before its own add; no spinning, no deadlock),
        // then device-scope f32 atomic accumulation.
        atomicCAS((unsigned int*)out, 0xAAAAAAAAu, 0u);
        atomicAdd(out, (float)mine);
    }
}

extern "C" void kernel_launch(void* const* d_in, const int* in_sizes, int n_in,
                              void* d_out, int out_size, void* d_ws, size_t ws_size,
                              hipStream_t stream) {
    const float* pc  = (const float*)d_in[0];   // predicted_class [64,900,14]
    const float* pbx = (const float*)d_in[1];   // predicted_bbox  [64,900,4]
    const int*   tl  = (const int*)  d_in[2];   // target_labels   [64,128]
    const float* tbx = (const float*)d_in[3];   // target_boxes    [64,128,4]
    (void)in_sizes; (void)n_in; (void)out_size; (void)d_ws; (void)ws_size;

    detr_hungarian_loss<<<dim3(B_), dim3(NTH), 0, stream>>>(pc, pbx, tl, tbx,
                                                            (float*)d_out);
}

// Round 6
// 187.656 us; speedup vs baseline: 3.4885x; 3.4885x over previous
//
#include <hip/hip_runtime.h>
#include <math.h>

// Problem constants (from reference): B=64, Q=900, T=128, NUM_CLASSES=13
#define B_    64
#define Q_    900
#define T_    128
#define NCLS  13
#define NCLS1 14
#define NTH   256
#define NWV   (NTH / 64)
#define NK    15          // wave0 scan: col q = lane + 64*k, k<NK

// Block-wide f64 sum; result valid on tid 0. All threads must call.
__device__ __forceinline__ double blockSum(double v, double* sAcc, int tid) {
#pragma unroll
    for (int off = 32; off > 0; off >>= 1) v += __shfl_down(v, off);
    if ((tid & 63) == 0) sAcc[tid >> 6] = v;
    __syncthreads();
    if (tid == 0) {
#pragma unroll
        for (int w = 1; w < NWV; ++w) v += sAcc[w];
    }
    __syncthreads();
    return v;
}

// f32 cost entry, identical op order to the jnp reference:
// (|dx|+|dy|+|dz|+|dw| summed left-to-right) - prob[lab].
__device__ __forceinline__ float costQ(const float4 p4, const float4 t4, const float pr) {
    float cb = fabsf(p4.x - t4.x);
    cb = cb + fabsf(p4.y - t4.y);
    cb = cb + fabsf(p4.z - t4.z);
    cb = cb + fabsf(p4.w - t4.w);
    return cb - pr;
}

// One block per image. Staging + row-minima use all 256 threads; the matching
// runs on wave 0 only:
//   greedy zero-reduced-cost init (row-min duals), then per free row an exact
//   dense Dijkstra SSP pass with DEFERRED dual updates (scan uses pass-start
//   u/v; one fix-up at pass end — algebraically the e-maxx JV totals) and
//   ALL-f32 path distances (ref is f64; flips need ~1e-7 ties, loss impact
//   ~1e-5 << threshold). Column state (boxes, v, minv) lives in registers of
//   the owning lane; argmin is a 6-step shuffle butterfly.
extern "C" __global__ __launch_bounds__(NTH, 1)
void detr_hungarian_loss(const float* __restrict__ pc,    // [B,Q,14]
                         const float* __restrict__ pbx,   // [B,Q,4]
                         const int*   __restrict__ tl,    // [B,T]
                         const float* __restrict__ tbx,   // [B,T,4]
                         float* __restrict__ out)         // [1], poisoned 0xAA
{
    const int b   = blockIdx.x;
    const int tid = threadIdx.x;

    __shared__ float  sProb[Q_ * NCLS];   // softmax probs, classes 0..12
    __shared__ float  sLse[Q_];           // logsumexp per query (for CE)
    __shared__ float4 sPb4[Q_];           // predicted boxes
    __shared__ float4 sTb4[T_];           // target boxes
    __shared__ int    sLab[T_];           // target labels
    __shared__ float  sU[T_];             // row duals (f32)
    __shared__ int    sP[Q_];             // col -> row+1, 0 = free
    __shared__ int    sWay[Q_];           // parent col per improved col; reused as tc[]
    __shared__ int    sAmin[T_];          // row -> argmin column
    __shared__ int    sFree[T_];
    __shared__ int    sNF;
    __shared__ int    sPred[T_];          // target t -> matched query
    __shared__ double sAcc[NWV];

    const float FINF = __builtin_inff();

    const float* pcb = pc  + (size_t)b * Q_ * NCLS1;
    const float* pbb = pbx + (size_t)b * Q_ * 4;
    const float* tbb = tbx + (size_t)b * T_ * 4;
    const int*   tlb = tl  + (size_t)b * T_;

    // ---- stage inputs + f32 softmax (same op order as jax.nn.softmax) ----
    for (int q = tid; q < Q_; q += NTH) {
        float x[NCLS1];
#pragma unroll
        for (int c = 0; c < NCLS1; ++c) x[c] = pcb[q * NCLS1 + c];
        float mx = x[0];
#pragma unroll
        for (int c = 1; c < NCLS1; ++c) mx = fmaxf(mx, x[c]);
        float ex[NCLS1];
        float sum = 0.f;
#pragma unroll
        for (int c = 0; c < NCLS1; ++c) { ex[c] = expf(x[c] - mx); sum += ex[c]; }
#pragma unroll
        for (int c = 0; c < NCLS; ++c) sProb[q * NCLS + c] = ex[c] / sum;
        sLse[q] = mx + logf(sum);
        sPb4[q] = reinterpret_cast<const float4*>(pbb)[q];
        sP[q] = 0;
    }
    for (int t = tid; t < T_; t += NTH) {
        sLab[t] = tlb[t];
        sTb4[t] = reinterpret_cast<const float4*>(tbb)[t];
    }
    __syncthreads();

    // ---- phase 1: row minima u[r] = min_j cost[r][j] + argmin column ----
    {
        const int r    = tid >> 1;        // 0..127, two threads per row
        const int half = tid & 1;
        const float4 t4  = sTb4[r];
        const int    lab = sLab[r];
        float bv = FINF;
        int   bj = Q_;
        const int q0 = half * (Q_ / 2);
        for (int q = q0; q < q0 + (Q_ / 2); ++q) {
            const float c = costQ(sPb4[q], t4, sProb[q * NCLS + lab]);
            if (c < bv) { bv = c; bj = q; }
        }
        const float ov = __shfl_xor(bv, 1);
        const int   oj = __shfl_xor(bj, 1);
        if (ov < bv || (ov == bv && oj < bj)) { bv = ov; bj = oj; }
        if (half == 0) { sU[r] = bv; sAmin[r] = bj; }
    }
    __syncthreads();

    // ============ wave 0 only: greedy init + deferred-dual SSP =============
    if (tid < 64) {
        const int lane = tid;
        const unsigned validMask = (lane < (Q_ - 64 * (NK - 1))) ? ((1u << NK) - 1u)
                                                                 : ((1u << (NK - 1)) - 1u);
        float4 pbr[NK];                   // owned predicted boxes
        float  v[NK];                     // owned column duals (pass-start)
#pragma unroll
        for (int k = 0; k < NK; ++k) {
            const int q = (k << 6) + lane;
            pbr[k] = (q < Q_) ? sPb4[q] : make_float4(0.f, 0.f, 0.f, 0.f);
            v[k] = 0.f;
        }

        // greedy zero-reduced-cost assignment (lane 0, serial)
        if (lane == 0) {
            int nf = 0;
            for (int r = 0; r < T_; ++r) {
                const int j = sAmin[r];
                if (sP[j] == 0) sP[j] = r + 1;
                else            sFree[nf++] = r;
            }
            sNF = nf;
        }
        __builtin_amdgcn_wave_barrier();
        const int nf = sNF;

        for (int fi = 0; fi < nf; ++fi) {
            const int rf = sFree[fi];
            float    minv[NK];
#pragma unroll
            for (int k = 0; k < NK; ++k) minv[k] = FINF;
            unsigned usedM   = ~validMask;
            unsigned poppedM = 0;
            int   i0row = rf;
            float dcur  = 0.f;
            int   jprev = -1;             // root marker
            float dT = 0.f; int jT = -1;

            for (int it = 0; it < 200; ++it) {
                const float  u0   = sU[i0row];
                const float4 t4   = sTb4[i0row];
                const int    lab  = sLab[i0row];
                const float  base = dcur - u0;

                float bestv = FINF;
                int   bestq = 1 << 29;
#pragma unroll
                for (int k = 0; k < NK; ++k) {
                    if (!((usedM >> k) & 1u)) {
                        const int   q    = (k << 6) + lane;
                        const float cost = costQ(pbr[k], t4, sProb[q * NCLS + lab]);
                        const float cur  = base + (cost - v[k]);
                        if (cur < minv[k]) { minv[k] = cur; sWay[q] = jprev; }
                        if (minv[k] < bestv) { bestv = minv[k]; bestq = q; }
                    }
                }
                // wave argmin, smallest-index ties; lands in every lane
#pragma unroll
                for (int m = 1; m < 64; m <<= 1) {
                    const float ov = __shfl_xor(bestv, m);
                    const int   oq = __shfl_xor(bestq, m);
                    if (ov < bestv || (ov == bestv && oq < bestq)) { bestv = ov; bestq = oq; }
                }
                // freeze popped column (minv stays = its distance)
                if ((bestq & 63) == lane) usedM |= 1u << (bestq >> 6);
                const int rowm = sP[bestq];
                __builtin_amdgcn_wave_barrier();
                if (rowm == 0) { dT = bestv; jT = bestq; break; }   // free col: done
                if ((bestq & 63) == lane) poppedM |= 1u << (bestq >> 6);
                jprev = bestq; i0row = rowm - 1; dcur = bestv;
            }

            // deferred dual updates (== e-maxx incremental totals), pre-augment
#pragma unroll
            for (int k = 0; k < NK; ++k) {
                if ((poppedM >> k) & 1u) {
                    const int q   = (k << 6) + lane;
                    const int row = sP[q] - 1;        // distinct rows, no race
                    sU[row] += dT - minv[k];
                    v[k]    += minv[k] - dT;
                }
            }
            if (lane == 0) sU[rf] += dT;
            __builtin_amdgcn_wave_barrier();
            if (lane == 0) {                           // augment along parents
                int jj = jT, guard = 0;
                while (guard++ < 200) {
                    const int jp = sWay[jj];
                    if (jp < 0) { sP[jj] = rf + 1; break; }
                    sP[jj] = sP[jp];
                    jj = jp;
                }
            }
            __builtin_amdgcn_wave_barrier();
        }
    }
    __syncthreads();

    // ---- extract matching: pred query for each target ----
    for (int q = tid; q < Q_; q += NTH) {
        const int pi = sP[q];
        if (pi > 0) sPred[pi - 1] = q;
    }
    __syncthreads();

    // ---- tc[] (reuse sWay): NUM_CLASSES default, matched queries get label ----
    int* sTc = sWay;
    for (int q = tid; q < Q_; q += NTH) sTc[q] = NCLS;
    __syncthreads();
    for (int t = tid; t < T_; t += NTH) sTc[sPred[t]] = sLab[t];  // sPred distinct
    __syncthreads();

    // ---- weighted CE over all queries ----
    double swn = 0.0, sw = 0.0;
    for (int q = tid; q < Q_; q += NTH) {
        const int   c   = sTc[q];
        const float xv  = pcb[q * NCLS1 + c];
        const float nll = sLse[q] - xv;              // -log_softmax[tc]
        const double w  = (c == NCLS) ? (double)0.05f : 1.0;
        swn += w * (double)nll;
        sw  += w;
    }

    // ---- bbox L1 + GIoU over matched pairs ----
    double l1s = 0.0, gs = 0.0;
    for (int t = tid; t < T_; t += NTH) {
        const int q = sPred[t];
        const float4 p4 = sPb4[q];
        const float4 t4 = sTb4[t];
        l1s += (double)fabsf(p4.x - t4.x) + (double)fabsf(p4.y - t4.y)
             + (double)fabsf(p4.z - t4.z) + (double)fabsf(p4.w - t4.w);
        const float ax1 = p4.x - 0.5f * p4.z, ay1 = p4.y - 0.5f * p4.w;
        const float ax2 = p4.x + 0.5f * p4.z, ay2 = p4.y + 0.5f * p4.w;
        const float bx1 = t4.x - 0.5f * t4.z, by1 = t4.y - 0.5f * t4.w;
        const float bx2 = t4.x + 0.5f * t4.z, by2 = t4.y + 0.5f * t4.w;
        const double a1 = (double)(ax2 - ax1) * (double)(ay2 - ay1);
        const double a2 = (double)(bx2 - bx1) * (double)(by2 - by1);
        const double ltx = fmax((double)ax1, (double)bx1);
        const double lty = fmax((double)ay1, (double)by1);
        const double rbx = fmin((double)ax2, (double)bx2);
        const double rby = fmin((double)ay2, (double)by2);
        const double iw = fmax(rbx - ltx, 0.0), ih = fmax(rby - lty, 0.0);
        const double inter = iw * ih;
        const double uni   = a1 + a2 - inter;
        const double iou   = inter / uni;
        const double cx1 = fmin((double)ax1, (double)bx1);
        const double cy1 = fmin((double)ay1, (double)by1);
        const double cx2 = fmax((double)ax2, (double)bx2);
        const double cy2 = fmax((double)ay2, (double)by2);
        const double ac  = (cx2 - cx1) * (cy2 - cy1);
        const double giou = iou - (ac - uni) / ac;
        gs += 1.0 - giou;
    }

    const double swnT = blockSum(swn, sAcc, tid);
    const double swT  = blockSum(sw,  sAcc, tid);
    const double l1T  = blockSum(l1s, sAcc, tid);
    const double gsT  = blockSum(gs,  sAcc, tid);
    if (tid == 0) {
        const double cls = swnT / swT;
        const double bb  = 5.0 * (l1T / (double)(T_ * 4)) + 2.0 * (gsT / (double)T_);
        const double mine = (cls + bb) / 8192.0;
        // fused finalize: CAS converts the 0xAA poison to 0.0 exactly once
        // (each block CASes before its own add; no spin), then atomic f32 sum.
        atomicCAS((unsigned int*)out, 0xAAAAAAAAu, 0u);
        atomicAdd(out, (float)mine);
    }
}

extern "C" void kernel_launch(void* const* d_in, const int* in_sizes, int n_in,
                              void* d_out, int out_size, void* d_ws, size_t ws_size,
                              hipStream_t stream) {
    const float* pc  = (const float*)d_in[0];   // predicted_class [64,900,14]
    const float* pbx = (const float*)d_in[1];   // predicted_bbox  [64,900,4]
    const int*   tl  = (const int*)  d_in[2];   // target_labels   [64,128]
    const float* tbx = (const float*)d_in[3];   // target_boxes    [64,128,4]
    (void)in_sizes; (void)n_in; (void)out_size; (void)d_ws; (void)ws_size;

    detr_hungarian_loss<<<dim3(B_), dim3(NTH), 0, stream>>>(pc, pbx, tl, tbx,
                                                            (float*)d_out);
}